// Round 21
// baseline (155.609 us; speedup 1.0000x reference)
//
#include <hip/hip_runtime.h>
#include <math.h>

typedef _Float16 f16;
typedef _Float16 f16x8 __attribute__((ext_vector_type(8)));
typedef _Float16 f16x4 __attribute__((ext_vector_type(4)));
typedef float f32x4 __attribute__((ext_vector_type(4)));

#define ROWS 88            // si row-dim stride (f16); rows 0..79 used
#define NTHREADS 64        // ONE wave per block: no barriers, fine scheduling

__device__ __forceinline__ float ssim_px(float m1, float m2, float mss, float m12) {
  const float C1 = 0.0001f, C2 = 0.0009f;
  const float mu1s = m1 * m1, mu2s = m2 * m2, mu12 = m1 * m2;
  const float num = (2.f * mu12 + C1) * (2.f * (m12 - mu12) + C2);
  const float den = (mu1s + mu2s + C1) * (mss - mu1s - mu2s + C2);
  return num * __builtin_amdgcn_rcpf(den);
}

// H phase: loads + f16 packed products + h-MFMA -> si (wave-private).
template <bool MASKED>
__device__ __forceinline__ void h_phase(
    const float* __restrict__ p1, const float* __restrict__ p2,
    f16 (*si)[16][ROWS],
    int gy0, int xb, int n, int kg, const f16x8& Bh)
{
#pragma unroll
  for (int rg = 0; rg < 5; rg++) {
    const int rimg = gy0 + rg * 16 + n;
    float okf;
    size_t base;
    if (MASKED) {
      const bool octok = (xb >= 0) && (xb <= 504);
      const bool rok = (rimg >= 0) && (rimg < 512);
      okf = (rok && octok) ? 1.f : 0.f;
      const int rc = rok ? rimg : 0;
      const int xc = octok ? xb : 0;
      base = ((size_t)rc << 9) + (size_t)xc;
    } else {
      okf = 1.f;
      base = ((size_t)rimg << 9) + (size_t)xb;
    }
    const float4 a0 = *(const float4*)(p1 + base);
    const float4 a1 = *(const float4*)(p1 + base + 4);
    const float4 b0 = *(const float4*)(p2 + base);
    const float4 b1 = *(const float4*)(p2 + base + 4);
    const float av[8] = {a0.x, a0.y, a0.z, a0.w, a1.x, a1.y, a1.z, a1.w};
    const float bw[8] = {b0.x, b0.y, b0.z, b0.w, b1.x, b1.y, b1.z, b1.w};
    f16x8 fa, fb;
#pragma unroll
    for (int i = 0; i < 8; i++) {
      float ai = av[i], bi = bw[i];
      if (MASKED) { ai *= okf; bi *= okf; }
      fa[i] = (f16)ai;
      fb[i] = (f16)bi;
    }
    const f16x8 fp = fa * fb;              // v_pk_mul_f16
    const f16x8 fs = fa * fa + fb * fb;    // v_pk_mul + v_pk_fma
    const f32x4 z = {0.f, 0.f, 0.f, 0.f};
    const f32x4 Da = __builtin_amdgcn_mfma_f32_16x16x32_f16(fa, Bh, z, 0, 0, 0);
    const f32x4 Db = __builtin_amdgcn_mfma_f32_16x16x32_f16(fb, Bh, z, 0, 0, 0);
    const f32x4 Ds = __builtin_amdgcn_mfma_f32_16x16x32_f16(fs, Bh, z, 0, 0, 0);
    const f32x4 Dp = __builtin_amdgcn_mfma_f32_16x16x32_f16(fp, Bh, z, 0, 0, 0);
    // D: col = lane&15 (= n = si column), row = kg*4+reg = local image row
    const int sr = rg * 16 + kg * 4;
    const f16x4 wa = {(f16)Da[0], (f16)Da[1], (f16)Da[2], (f16)Da[3]};
    const f16x4 wb = {(f16)Db[0], (f16)Db[1], (f16)Db[2], (f16)Db[3]};
    const f16x4 ws = {(f16)Ds[0], (f16)Ds[1], (f16)Ds[2], (f16)Ds[3]};
    const f16x4 wp = {(f16)Dp[0], (f16)Dp[1], (f16)Dp[2], (f16)Dp[3]};
    *(f16x4*)&si[0][n][sr] = wa;
    *(f16x4*)&si[1][n][sr] = wb;
    *(f16x4*)&si[2][n][sr] = ws;
    *(f16x4*)&si[3][n][sr] = wp;
  }
}

__global__ __launch_bounds__(NTHREADS) void ssim_main_kernel(
    const float* __restrict__ img1, const float* __restrict__ img2,
    float* __restrict__ partials, float norm, float cexp)
{
  // wave-private h-blur fields: si[field][px(16)][row(88)], f16. 11,264 B.
  // Whole kernel is barrier-free: same-wave DS write->read is ordered by HW.
  __shared__ f16 si[4][16][ROWS];

  const int lane = threadIdx.x;          // one wave
  const int n = lane & 15, kg = lane >> 4;

  // block = one 16x64 strip: xo fastest (adjacent strips share halo in L1/L2)
  int b = blockIdx.x;
  const int xo = b & 3; b >>= 2;
  const int tx = b & 7; b >>= 3;
  const int ty = b & 7; b >>= 3;
  const float* __restrict__ p1 = img1 + (size_t)b * 262144;
  const float* __restrict__ p2 = img2 + (size_t)b * 262144;

  // ---- constant tap fragments ----
  // h: B[k][n] = g[k-n-3]; v: A[o][kr] = g[kr-o]; k = 8*kg+i
  f16x8 Bh, Av;
#pragma unroll
  for (int i = 0; i < 8; i++) {
    const int k = 8 * kg + i;
    {
      const int idx = k - n - 3;
      const float d = (float)(idx - 5);
      const float val = norm * exp2f(cexp * d * d);
      Bh[i] = (idx >= 0 && idx <= 10) ? (f16)val : (f16)0.f;
    }
    {
      const int idx = k - n;
      const float d = (float)(idx - 5);
      const float val = norm * exp2f(cexp * d * d);
      Av[i] = (idx >= 0 && idx <= 10) ? (f16)val : (f16)0.f;
    }
  }

  // ---- geometry ----
  const int X0 = tx * 64 + xo * 16;      // strip's out-x base
  const int xb = X0 - 8 + 8 * kg;        // lane's sample-octet base
  const int gy0 = ty * 64 - 5;

  // ================= H phase (barrier-free) =================
  const bool interior = !((tx == 0) & (xo == 0)) && !((tx == 7) & (xo == 3)) &&
                        (ty >= 1) && (ty <= 6);
  if (interior)
    h_phase<false>(p1, p2, si, gy0, xb, n, kg, Bh);
  else
    h_phase<true>(p1, p2, si, gy0, xb, n, kg, Bh);

  // ================= V phase: 4 output-row groups of 16 =================
  float acc4[4] = {0.f, 0.f, 0.f, 0.f};
#pragma unroll
  for (int og = 0; og < 4; og++) {
    const int srb = og * 16 + 8 * kg;    // B k-slice rows (contiguous 8)
    const f16x8 Ba = *(const f16x8*)&si[0][n][srb];
    const f16x8 Bb = *(const f16x8*)&si[1][n][srb];
    const f16x8 Bs = *(const f16x8*)&si[2][n][srb];
    const f16x8 Bp = *(const f16x8*)&si[3][n][srb];
    const f32x4 z = {0.f, 0.f, 0.f, 0.f};
    const f32x4 Ma = __builtin_amdgcn_mfma_f32_16x16x32_f16(Av, Ba, z, 0, 0, 0);
    const f32x4 Mb = __builtin_amdgcn_mfma_f32_16x16x32_f16(Av, Bb, z, 0, 0, 0);
    const f32x4 Ms = __builtin_amdgcn_mfma_f32_16x16x32_f16(Av, Bs, z, 0, 0, 0);
    const f32x4 Mp = __builtin_amdgcn_mfma_f32_16x16x32_f16(Av, Bp, z, 0, 0, 0);
#pragma unroll
    for (int r = 0; r < 4; r++)
      acc4[r] += ssim_px(Ma[r], Mb[r], Ms[r], Mp[r]);
  }
  float accSum = (acc4[0] + acc4[1]) + (acc4[2] + acc4[3]);

  // ---- wave reduction only ----
  for (int off = 32; off > 0; off >>= 1)
    accSum += __shfl_down(accSum, off, 64);
  if (lane == 0)
    partials[blockIdx.x] = accSum;
}

__global__ __launch_bounds__(256) void ssim_final_kernel(
    const float* __restrict__ partials, float* __restrict__ out,
    int n, double invN)
{
  __shared__ double sred[4];
  const int tid = threadIdx.x;
  double s = 0.0;
  for (int i = tid; i < n; i += 256) s += (double)partials[i];
  for (int off = 32; off > 0; off >>= 1)
    s += __shfl_down(s, off, 64);
  if ((tid & 63) == 0) sred[tid >> 6] = s;
  __syncthreads();
  if (tid == 0) {
    double tot = 0.0;
#pragma unroll
    for (int i = 0; i < 4; i++) tot += sred[i];
    out[0] = (float)(1.0 - tot * invN);
  }
}

extern "C" void kernel_launch(void* const* d_in, const int* in_sizes, int n_in,
                              void* d_out, int out_size, void* d_ws, size_t ws_size,
                              hipStream_t stream) {
  const float* img1 = (const float*)d_in[0];
  const float* img2 = (const float*)d_in[1];
  float* out = (float*)d_out;
  float* partials = (float*)d_ws;

  const int planes = in_sizes[0] / (512 * 512);   // 96
  const int nBlocks = planes * 8 * 8 * 4;         // 24576 one-wave strips

  // taps: g(idx) = norm * exp2(cexp * (idx-5)^2), idx in [0,10]
  double sum = 0.0;
  for (int i = 0; i < 11; i++) {
    const double x = (double)(i - 5);
    sum += exp(-(x * x) / 4.5);
  }
  const float norm = (float)(1.0 / sum);
  const float cexp = (float)(-1.0 / (4.5 * 0.6931471805599453));

  const double invN = 1.0 / (double)in_sizes[0];

  ssim_main_kernel<<<nBlocks, NTHREADS, 0, stream>>>(img1, img2, partials, norm, cexp);
  ssim_final_kernel<<<1, 256, 0, stream>>>(partials, out, nBlocks, invN);
}

// Round 22
// 110.650 us; speedup vs baseline: 1.4063x; 1.4063x over previous
//
#include <hip/hip_runtime.h>
#include <math.h>

typedef _Float16 f16;
typedef _Float16 f16x8 __attribute__((ext_vector_type(8)));
typedef _Float16 f16x4 __attribute__((ext_vector_type(4)));
typedef float f32x4 __attribute__((ext_vector_type(4)));

#define ROWS 88            // si row-dim stride (f16); rows 0..79 used
#define NTHREADS 256

__device__ __forceinline__ float ssim_px(float m1, float m2, float mss, float m12) {
  const float C1 = 0.0001f, C2 = 0.0009f;
  const float mu1s = m1 * m1, mu2s = m2 * m2, mu12 = m1 * m2;
  const float num = (2.f * mu12 + C1) * (2.f * (m12 - mu12) + C2);
  const float den = (mu1s + mu2s + C1) * (mss - mu1s - mu2s + C2);
  return num * __builtin_amdgcn_rcpf(den);
}

// Issue all 20 loads for one tile into named registers.
template <bool MASKED>
__device__ __forceinline__ void issue_loads(
    const float* __restrict__ p1, const float* __restrict__ p2,
    int gy0, int xb, int n,
    float4 La0[5], float4 La1[5], float4 Lb0[5], float4 Lb1[5], float okf[5])
{
#pragma unroll
  for (int rg = 0; rg < 5; rg++) {
    const int rimg = gy0 + rg * 16 + n;
    size_t base;
    if (MASKED) {
      const bool octok = (xb >= 0) && (xb <= 504);
      const bool rok = (rimg >= 0) && (rimg < 512);
      okf[rg] = (rok && octok) ? 1.f : 0.f;
      const int rc = rok ? rimg : 0;
      const int xc = octok ? xb : 0;
      base = ((size_t)rc << 9) + (size_t)xc;
    } else {
      okf[rg] = 1.f;
      base = ((size_t)rimg << 9) + (size_t)xb;
    }
    La0[rg] = *(const float4*)(p1 + base);
    La1[rg] = *(const float4*)(p1 + base + 4);
    Lb0[rg] = *(const float4*)(p2 + base);
    Lb1[rg] = *(const float4*)(p2 + base + 4);
  }
}

// Consume staged registers: f16 packed products + h-MFMA -> si (wave-private).
template <bool MASKED>
__device__ __forceinline__ void h_consume(
    const float4 La0[5], const float4 La1[5],
    const float4 Lb0[5], const float4 Lb1[5], const float okf[5],
    f16 (*si)[64][ROWS], int px, int kg, const f16x8& Bh)
{
#pragma unroll
  for (int rg = 0; rg < 5; rg++) {
    const float av[8] = {La0[rg].x, La0[rg].y, La0[rg].z, La0[rg].w,
                         La1[rg].x, La1[rg].y, La1[rg].z, La1[rg].w};
    const float bw[8] = {Lb0[rg].x, Lb0[rg].y, Lb0[rg].z, Lb0[rg].w,
                         Lb1[rg].x, Lb1[rg].y, Lb1[rg].z, Lb1[rg].w};
    f16x8 fa, fb;
#pragma unroll
    for (int i = 0; i < 8; i++) {
      float ai = av[i], bi = bw[i];
      if (MASKED) { ai *= okf[rg]; bi *= okf[rg]; }
      fa[i] = (f16)ai;
      fb[i] = (f16)bi;
    }
    const f16x8 fp = fa * fb;              // v_pk_mul_f16
    const f16x8 fs = fa * fa + fb * fb;    // v_pk_mul + v_pk_fma
    const f32x4 z = {0.f, 0.f, 0.f, 0.f};
    const f32x4 Da = __builtin_amdgcn_mfma_f32_16x16x32_f16(fa, Bh, z, 0, 0, 0);
    const f32x4 Db = __builtin_amdgcn_mfma_f32_16x16x32_f16(fb, Bh, z, 0, 0, 0);
    const f32x4 Ds = __builtin_amdgcn_mfma_f32_16x16x32_f16(fs, Bh, z, 0, 0, 0);
    const f32x4 Dp = __builtin_amdgcn_mfma_f32_16x16x32_f16(fp, Bh, z, 0, 0, 0);
    // D: col = lane&15 (-> px), row = kg*4+reg = local image row
    const int sr = rg * 16 + kg * 4;
    const f16x4 wa = {(f16)Da[0], (f16)Da[1], (f16)Da[2], (f16)Da[3]};
    const f16x4 wb = {(f16)Db[0], (f16)Db[1], (f16)Db[2], (f16)Db[3]};
    const f16x4 ws = {(f16)Ds[0], (f16)Ds[1], (f16)Ds[2], (f16)Ds[3]};
    const f16x4 wp = {(f16)Dp[0], (f16)Dp[1], (f16)Dp[2], (f16)Dp[3]};
    *(f16x4*)&si[0][px][sr] = wa;
    *(f16x4*)&si[1][px][sr] = wb;
    *(f16x4*)&si[2][px][sr] = ws;
    *(f16x4*)&si[3][px][sr] = wp;
  }
}

__device__ __forceinline__ void v_phase(
    f16 (*si)[64][ROWS], int px, int kg, const f16x8& Av, float acc4[4])
{
#pragma unroll
  for (int og = 0; og < 4; og++) {
    const int srb = og * 16 + 8 * kg;    // B k-slice rows (contiguous 8)
    const f16x8 Ba = *(const f16x8*)&si[0][px][srb];
    const f16x8 Bb = *(const f16x8*)&si[1][px][srb];
    const f16x8 Bs = *(const f16x8*)&si[2][px][srb];
    const f16x8 Bp = *(const f16x8*)&si[3][px][srb];
    const f32x4 z = {0.f, 0.f, 0.f, 0.f};
    const f32x4 Ma = __builtin_amdgcn_mfma_f32_16x16x32_f16(Av, Ba, z, 0, 0, 0);
    const f32x4 Mb = __builtin_amdgcn_mfma_f32_16x16x32_f16(Av, Bb, z, 0, 0, 0);
    const f32x4 Ms = __builtin_amdgcn_mfma_f32_16x16x32_f16(Av, Bs, z, 0, 0, 0);
    const f32x4 Mp = __builtin_amdgcn_mfma_f32_16x16x32_f16(Av, Bp, z, 0, 0, 0);
#pragma unroll
    for (int r = 0; r < 4; r++)
      acc4[r] += ssim_px(Ma[r], Mb[r], Ms[r], Mp[r]);
  }
}

__global__ __launch_bounds__(NTHREADS) void ssim_main_kernel(
    const float* __restrict__ img1, const float* __restrict__ img2,
    float* __restrict__ partials, float norm, float cexp)
{
  // transposed h-blur fields: si[field][px(64)][row(88)], f16. 45,056 B.
  // Columns [16*wv,16*wv+16) are PRIVATE to wave wv (written in h, read in v
  // by the same wave) -> NO barriers in the whole pipeline; same-wave DS ops
  // execute in order (verified R20: absmax 0).
  __shared__ f16 si[4][64][ROWS];
  __shared__ float sred[4];

  const int tid = threadIdx.x;
  const int wv = tid >> 6, lane = tid & 63;
  const int n = lane & 15, kg = lane >> 4;

  // two tiles per block: same (tx,ty), planes q and q+48
  int b = blockIdx.x;
  const int tx = b & 7; b >>= 3;
  const int ty = b & 7; b >>= 3;
  const float* __restrict__ p1A = img1 + (size_t)b * 262144;
  const float* __restrict__ p2A = img2 + (size_t)b * 262144;
  const float* __restrict__ p1B = p1A + (size_t)48 * 262144;
  const float* __restrict__ p2B = p2A + (size_t)48 * 262144;

  // ---- constant tap fragments ----
  // h: B[k][n] = g[k-n-3]; v: A[o][kr] = g[kr-o]; k = 8*kg+i
  f16x8 Bh, Av;
#pragma unroll
  for (int i = 0; i < 8; i++) {
    const int k = 8 * kg + i;
    {
      const int idx = k - n - 3;
      const float d = (float)(idx - 5);
      const float val = norm * exp2f(cexp * d * d);
      Bh[i] = (idx >= 0 && idx <= 10) ? (f16)val : (f16)0.f;
    }
    {
      const int idx = k - n;
      const float d = (float)(idx - 5);
      const float val = norm * exp2f(cexp * d * d);
      Av[i] = (idx >= 0 && idx <= 10) ? (f16)val : (f16)0.f;
    }
  }

  // ---- geometry (identical for both tiles) ----
  const int X0 = tx * 64 + wv * 16;
  const int xb = X0 - 8 + 8 * kg;
  const int gy0 = ty * 64 - 5;
  const int px = wv * 16 + n;
  const bool interior = (tx >= 1) && (tx <= 6) && (ty >= 1) && (ty <= 6);

  float acc4[4] = {0.f, 0.f, 0.f, 0.f};
  float4 La0[5], La1[5], Lb0[5], Lb1[5];
  float okf[5];

  // ---- tile A: load + h ----
  if (interior) {
    issue_loads<false>(p1A, p2A, gy0, xb, n, La0, La1, Lb0, Lb1, okf);
    h_consume<false>(La0, La1, Lb0, Lb1, okf, si, px, kg, Bh);
  } else {
    issue_loads<true>(p1A, p2A, gy0, xb, n, La0, La1, Lb0, Lb1, okf);
    h_consume<true>(La0, La1, Lb0, Lb1, okf, si, px, kg, Bh);
  }

  // ---- prefetch tile B (pinned; stays in flight across v(A)) ----
  __builtin_amdgcn_sched_barrier(0);
  if (interior)
    issue_loads<false>(p1B, p2B, gy0, xb, n, La0, La1, Lb0, Lb1, okf);
  else
    issue_loads<true>(p1B, p2B, gy0, xb, n, La0, La1, Lb0, Lb1, okf);
  __builtin_amdgcn_sched_barrier(0);

  // ---- tile A: v (no barrier: si wave-private) ----
  v_phase(si, px, kg, Av, acc4);

  // ---- tile B: h (same-wave DS order guards si reuse) ----
  if (interior)
    h_consume<false>(La0, La1, Lb0, Lb1, okf, si, px, kg, Bh);
  else
    h_consume<true>(La0, La1, Lb0, Lb1, okf, si, px, kg, Bh);

  // ---- tile B: v ----
  v_phase(si, px, kg, Av, acc4);

  float accSum = (acc4[0] + acc4[1]) + (acc4[2] + acc4[3]);

  // ---- block reduction (only barrier in the kernel) ----
  for (int off = 32; off > 0; off >>= 1)
    accSum += __shfl_down(accSum, off, 64);
  if (lane == 0) sred[wv] = accSum;
  __syncthreads();
  if (tid == 0)
    partials[blockIdx.x] = sred[0] + sred[1] + sred[2] + sred[3];
}

__global__ __launch_bounds__(256) void ssim_final_kernel(
    const float* __restrict__ partials, float* __restrict__ out,
    int n, double invN)
{
  __shared__ double sred[4];
  const int tid = threadIdx.x;
  double s = 0.0;
  for (int i = tid; i < n; i += 256) s += (double)partials[i];
  for (int off = 32; off > 0; off >>= 1)
    s += __shfl_down(s, off, 64);
  if ((tid & 63) == 0) sred[tid >> 6] = s;
  __syncthreads();
  if (tid == 0) {
    double tot = 0.0;
#pragma unroll
    for (int i = 0; i < 4; i++) tot += sred[i];
    out[0] = (float)(1.0 - tot * invN);
  }
}

extern "C" void kernel_launch(void* const* d_in, const int* in_sizes, int n_in,
                              void* d_out, int out_size, void* d_ws, size_t ws_size,
                              hipStream_t stream) {
  const float* img1 = (const float*)d_in[0];
  const float* img2 = (const float*)d_in[1];
  float* out = (float*)d_out;
  float* partials = (float*)d_ws;

  const int planes = in_sizes[0] / (512 * 512);   // 96
  const int nBlocks = (planes / 2) * 8 * 8;       // 3072, two tiles each

  // taps: g(idx) = norm * exp2(cexp * (idx-5)^2), idx in [0,10]
  double sum = 0.0;
  for (int i = 0; i < 11; i++) {
    const double x = (double)(i - 5);
    sum += exp(-(x * x) / 4.5);
  }
  const float norm = (float)(1.0 / sum);
  const float cexp = (float)(-1.0 / (4.5 * 0.6931471805599453));

  const double invN = 1.0 / (double)in_sizes[0];

  ssim_main_kernel<<<nBlocks, NTHREADS, 0, stream>>>(img1, img2, partials, norm, cexp);
  ssim_final_kernel<<<1, 256, 0, stream>>>(partials, out, nBlocks, invN);
}

// Round 23
// 86.164 us; speedup vs baseline: 1.8060x; 1.2842x over previous
//
#include <hip/hip_runtime.h>
#include <math.h>

typedef _Float16 f16;
typedef _Float16 f16x8 __attribute__((ext_vector_type(8)));
typedef _Float16 f16x4 __attribute__((ext_vector_type(4)));
typedef float f32x4 __attribute__((ext_vector_type(4)));

#define ROWS 52            // si row-dim stride (f16): 104 B -> 16 start banks
#define NTHREADS 256

__device__ __forceinline__ float ssim_px(float m1, float m2, float mss, float m12) {
  const float C1 = 0.0001f, C2 = 0.0009f;
  const float mu1s = m1 * m1, mu2s = m2 * m2, mu12 = m1 * m2;
  const float num = (2.f * mu12 + C1) * (2.f * (m12 - mu12) + C2);
  const float den = (mu1s + mu2s + C1) * (mss - mu1s - mu2s + C2);
  return num * __builtin_amdgcn_rcpf(den);
}

// H phase: 3 row-groups (48 rows; rows 42..47 are annihilated by zero taps
// in the v band matrix, so no extra masking needed beyond image bounds).
template <bool MASKED>
__device__ __forceinline__ void h_phase(
    const float* __restrict__ p1, const float* __restrict__ p2,
    f16 (*si)[64][ROWS],
    int gy0, int xb, int px, int n, int kg, const f16x8& Bh)
{
#pragma unroll
  for (int rg = 0; rg < 3; rg++) {
    const int rimg = gy0 + rg * 16 + n;
    float okf;
    size_t base;
    if (MASKED) {
      const bool octok = (xb >= 0) && (xb <= 504);
      const bool rok = (rimg >= 0) && (rimg < 512);
      okf = (rok && octok) ? 1.f : 0.f;
      const int rc = rok ? rimg : 0;
      const int xc = octok ? xb : 0;
      base = ((size_t)rc << 9) + (size_t)xc;
    } else {
      okf = 1.f;
      base = ((size_t)rimg << 9) + (size_t)xb;
    }
    const float4 a0 = *(const float4*)(p1 + base);
    const float4 a1 = *(const float4*)(p1 + base + 4);
    const float4 b0 = *(const float4*)(p2 + base);
    const float4 b1 = *(const float4*)(p2 + base + 4);
    const float av[8] = {a0.x, a0.y, a0.z, a0.w, a1.x, a1.y, a1.z, a1.w};
    const float bw[8] = {b0.x, b0.y, b0.z, b0.w, b1.x, b1.y, b1.z, b1.w};
    f16x8 fa, fb;
#pragma unroll
    for (int i = 0; i < 8; i++) {
      float ai = av[i], bi = bw[i];
      if (MASKED) { ai *= okf; bi *= okf; }
      fa[i] = (f16)ai;
      fb[i] = (f16)bi;
    }
    const f16x8 fp = fa * fb;              // v_pk_mul_f16
    const f16x8 fs = fa * fa + fb * fb;    // v_pk_mul + v_pk_fma
    const f32x4 z = {0.f, 0.f, 0.f, 0.f};
    const f32x4 Da = __builtin_amdgcn_mfma_f32_16x16x32_f16(fa, Bh, z, 0, 0, 0);
    const f32x4 Db = __builtin_amdgcn_mfma_f32_16x16x32_f16(fb, Bh, z, 0, 0, 0);
    const f32x4 Ds = __builtin_amdgcn_mfma_f32_16x16x32_f16(fs, Bh, z, 0, 0, 0);
    const f32x4 Dp = __builtin_amdgcn_mfma_f32_16x16x32_f16(fp, Bh, z, 0, 0, 0);
    // D: col = lane&15 (-> px), row = kg*4+reg = local image row
    const int sr = rg * 16 + kg * 4;
    const f16x4 wa = {(f16)Da[0], (f16)Da[1], (f16)Da[2], (f16)Da[3]};
    const f16x4 wb = {(f16)Db[0], (f16)Db[1], (f16)Db[2], (f16)Db[3]};
    const f16x4 ws = {(f16)Ds[0], (f16)Ds[1], (f16)Ds[2], (f16)Ds[3]};
    const f16x4 wp = {(f16)Dp[0], (f16)Dp[1], (f16)Dp[2], (f16)Dp[3]};
    *(f16x4*)&si[0][px][sr] = wa;
    *(f16x4*)&si[1][px][sr] = wb;
    *(f16x4*)&si[2][px][sr] = ws;
    *(f16x4*)&si[3][px][sr] = wp;
  }
}

__global__ __launch_bounds__(NTHREADS) void ssim_main_kernel(
    const float* __restrict__ img1, const float* __restrict__ img2,
    float* __restrict__ partials, float norm, float cexp)
{
  // transposed h-blur fields: si[field][px(64)][row(52 stride)], f16. 26,624 B
  // -> 6 blocks/CU = 24 waves/CU. Columns [16wv,16wv+16) PRIVATE to wave wv;
  // barrier-free pipeline (same-wave DS ordering; verified R20 absmax 0).
  __shared__ f16 si[4][64][ROWS];
  __shared__ float sred[4];

  const int tid = threadIdx.x;
  const int wv = tid >> 6, lane = tid & 63;
  const int n = lane & 15, kg = lane >> 4;

  int b = blockIdx.x;
  const int tx = b & 7;  b >>= 3;
  const int ty = b & 15; b >>= 4;
  const float* __restrict__ p1 = img1 + (size_t)b * 262144;
  const float* __restrict__ p2 = img2 + (size_t)b * 262144;

  // ---- constant tap fragments ----
  // h: B[k][n] = g[k-n-3]; v: A[o][kr] = g[kr-o]; k = 8*kg+i
  f16x8 Bh, Av;
#pragma unroll
  for (int i = 0; i < 8; i++) {
    const int k = 8 * kg + i;
    {
      const int idx = k - n - 3;
      const float d = (float)(idx - 5);
      const float val = norm * exp2f(cexp * d * d);
      Bh[i] = (idx >= 0 && idx <= 10) ? (f16)val : (f16)0.f;
    }
    {
      const int idx = k - n;
      const float d = (float)(idx - 5);
      const float val = norm * exp2f(cexp * d * d);
      Av[i] = (idx >= 0 && idx <= 10) ? (f16)val : (f16)0.f;
    }
  }

  // ---- geometry ----
  const int X0 = tx * 64 + wv * 16;      // this wave's out-x base
  const int xb = X0 - 8 + 8 * kg;        // this lane's sample-octet base
  const int gy0 = ty * 32 - 5;
  const int px = wv * 16 + n;            // this lane's si column

  // ================= H phase (barrier-free) =================
  // interior: all 48 rows in-bounds (gy0 >= 0 and gy0+47 <= 511) and x-octets ok
  const bool interior = (tx >= 1) && (tx <= 6) && (ty >= 1) && (ty <= 14);
  if (interior)
    h_phase<false>(p1, p2, si, gy0, xb, px, n, kg, Bh);
  else
    h_phase<true>(p1, p2, si, gy0, xb, px, n, kg, Bh);

  // ================= V phase: 2 output-row groups of 16 =================
  float acc4[4] = {0.f, 0.f, 0.f, 0.f};
#pragma unroll
  for (int og = 0; og < 2; og++) {
    const int srb = og * 16 + 8 * kg;    // B k-slice rows (contiguous 8)
    const f16x8 Ba = *(const f16x8*)&si[0][px][srb];
    const f16x8 Bb = *(const f16x8*)&si[1][px][srb];
    const f16x8 Bs = *(const f16x8*)&si[2][px][srb];
    const f16x8 Bp = *(const f16x8*)&si[3][px][srb];
    const f32x4 z = {0.f, 0.f, 0.f, 0.f};
    const f32x4 Ma = __builtin_amdgcn_mfma_f32_16x16x32_f16(Av, Ba, z, 0, 0, 0);
    const f32x4 Mb = __builtin_amdgcn_mfma_f32_16x16x32_f16(Av, Bb, z, 0, 0, 0);
    const f32x4 Ms = __builtin_amdgcn_mfma_f32_16x16x32_f16(Av, Bs, z, 0, 0, 0);
    const f32x4 Mp = __builtin_amdgcn_mfma_f32_16x16x32_f16(Av, Bp, z, 0, 0, 0);
    // D: col = x (lane&15), row = out-row og*16 + kg*4 + reg
#pragma unroll
    for (int r = 0; r < 4; r++)
      acc4[r] += ssim_px(Ma[r], Mb[r], Ms[r], Mp[r]);
  }
  float accSum = (acc4[0] + acc4[1]) + (acc4[2] + acc4[3]);

  // ---- block reduction (only barrier in the kernel) ----
  for (int off = 32; off > 0; off >>= 1)
    accSum += __shfl_down(accSum, off, 64);
  if (lane == 0) sred[wv] = accSum;
  __syncthreads();
  if (tid == 0)
    partials[blockIdx.x] = sred[0] + sred[1] + sred[2] + sred[3];
}

__global__ __launch_bounds__(256) void ssim_final_kernel(
    const float* __restrict__ partials, float* __restrict__ out,
    int n, double invN)
{
  __shared__ double sred[4];
  const int tid = threadIdx.x;
  double s = 0.0;
  for (int i = tid; i < n; i += 256) s += (double)partials[i];
  for (int off = 32; off > 0; off >>= 1)
    s += __shfl_down(s, off, 64);
  if ((tid & 63) == 0) sred[tid >> 6] = s;
  __syncthreads();
  if (tid == 0) {
    double tot = 0.0;
#pragma unroll
    for (int i = 0; i < 4; i++) tot += sred[i];
    out[0] = (float)(1.0 - tot * invN);
  }
}

extern "C" void kernel_launch(void* const* d_in, const int* in_sizes, int n_in,
                              void* d_out, int out_size, void* d_ws, size_t ws_size,
                              hipStream_t stream) {
  const float* img1 = (const float*)d_in[0];
  const float* img2 = (const float*)d_in[1];
  float* out = (float*)d_out;
  float* partials = (float*)d_ws;

  const int planes = in_sizes[0] / (512 * 512);   // 96
  const int nBlocks = planes * 8 * 16;            // 12288 (64x32 tiles)

  // taps: g(idx) = norm * exp2(cexp * (idx-5)^2), idx in [0,10]
  double sum = 0.0;
  for (int i = 0; i < 11; i++) {
    const double x = (double)(i - 5);
    sum += exp(-(x * x) / 4.5);
  }
  const float norm = (float)(1.0 / sum);
  const float cexp = (float)(-1.0 / (4.5 * 0.6931471805599453));

  const double invN = 1.0 / (double)in_sizes[0];

  ssim_main_kernel<<<nBlocks, NTHREADS, 0, stream>>>(img1, img2, partials, norm, cexp);
  ssim_final_kernel<<<1, 256, 0, stream>>>(partials, out, nBlocks, invN);
}

// Round 24
// 73.331 us; speedup vs baseline: 2.1220x; 1.1750x over previous
//
#include <hip/hip_runtime.h>
#include <math.h>

typedef _Float16 f16;
typedef _Float16 f16x2 __attribute__((ext_vector_type(2)));
typedef _Float16 f16x8 __attribute__((ext_vector_type(8)));
typedef _Float16 f16x4 __attribute__((ext_vector_type(4)));
typedef float f32x4 __attribute__((ext_vector_type(4)));

#define ROWS 88            // si row-dim stride (f16); rows 0..79 used
#define NTHREADS 256

__device__ __forceinline__ float ssim_px(float m1, float m2, float mss, float m12) {
  const float C1 = 0.0001f, C2 = 0.0009f;
  const float mu1s = m1 * m1, mu2s = m2 * m2, mu12 = m1 * m2;
  const float num = (2.f * mu12 + C1) * (2.f * (m12 - mu12) + C2);
  const float den = (mu1s + mu2s + C1) * (mss - mu1s - mu2s + C2);
  return num * __builtin_amdgcn_rcpf(den);
}

__device__ __forceinline__ unsigned pk2(float a, float b) {
  return __builtin_bit_cast(unsigned, __builtin_amdgcn_cvt_pkrtz(a, b));
}

// ---- 2-deep rolling h pipeline: issue group RG into slot S ----
#define H_ISSUE(RG, S)                                                         \
  {                                                                            \
    const int rimg = gy0 + (RG) * 16 + n;                                      \
    size_t base;                                                               \
    if (MASKED) {                                                              \
      const bool octok = (xb >= 0) && (xb <= 504);                             \
      const bool rok = (rimg >= 0) && (rimg < 512);                            \
      ok[S] = (rok && octok) ? 1.f : 0.f;                                      \
      base = ((size_t)(rok ? rimg : 0) << 9) + (size_t)(octok ? xb : 0);       \
    } else {                                                                   \
      ok[S] = 1.f;                                                             \
      base = ((size_t)rimg << 9) + (size_t)xb;                                 \
    }                                                                          \
    A0[S] = *(const float4*)(p1 + base);                                       \
    A1[S] = *(const float4*)(p1 + base + 4);                                   \
    B0[S] = *(const float4*)(p2 + base);                                       \
    B1[S] = *(const float4*)(p2 + base + 4);                                   \
  }

// ---- consume slot S (group RG): packed cvt + pk products + 4 MFMA + write --
#define H_CONSUME(RG, S)                                                       \
  {                                                                            \
    float4 a0 = A0[S], a1 = A1[S], b0 = B0[S], b1 = B1[S];                     \
    if (MASKED) {                                                              \
      const float m = ok[S];                                                   \
      a0.x *= m; a0.y *= m; a0.z *= m; a0.w *= m;                              \
      a1.x *= m; a1.y *= m; a1.z *= m; a1.w *= m;                              \
      b0.x *= m; b0.y *= m; b0.z *= m; b0.w *= m;                              \
      b1.x *= m; b1.y *= m; b1.z *= m; b1.w *= m;                              \
    }                                                                          \
    union { f16x8 v; unsigned u[4]; } ua, ub;                                  \
    ua.u[0] = pk2(a0.x, a0.y); ua.u[1] = pk2(a0.z, a0.w);                      \
    ua.u[2] = pk2(a1.x, a1.y); ua.u[3] = pk2(a1.z, a1.w);                      \
    ub.u[0] = pk2(b0.x, b0.y); ub.u[1] = pk2(b0.z, b0.w);                      \
    ub.u[2] = pk2(b1.x, b1.y); ub.u[3] = pk2(b1.z, b1.w);                      \
    const f16x8 fa = ua.v, fb = ub.v;                                          \
    const f16x8 fp = fa * fb;              /* v_pk_mul_f16 */                  \
    const f16x8 fs = fa * fa + fb * fb;    /* v_pk_mul + v_pk_fma */           \
    const f32x4 z = {0.f, 0.f, 0.f, 0.f};                                      \
    const f32x4 Da = __builtin_amdgcn_mfma_f32_16x16x32_f16(fa, Bh, z, 0, 0, 0); \
    const f32x4 Db = __builtin_amdgcn_mfma_f32_16x16x32_f16(fb, Bh, z, 0, 0, 0); \
    const f32x4 Ds = __builtin_amdgcn_mfma_f32_16x16x32_f16(fs, Bh, z, 0, 0, 0); \
    const f32x4 Dp = __builtin_amdgcn_mfma_f32_16x16x32_f16(fp, Bh, z, 0, 0, 0); \
    const int sr = (RG) * 16 + kg * 4;                                         \
    const f16x4 wa = {(f16)Da[0], (f16)Da[1], (f16)Da[2], (f16)Da[3]};         \
    const f16x4 wb = {(f16)Db[0], (f16)Db[1], (f16)Db[2], (f16)Db[3]};         \
    const f16x4 ws = {(f16)Ds[0], (f16)Ds[1], (f16)Ds[2], (f16)Ds[3]};         \
    const f16x4 wp = {(f16)Dp[0], (f16)Dp[1], (f16)Dp[2], (f16)Dp[3]};         \
    *(f16x4*)&si[0][px][sr] = wa;                                              \
    *(f16x4*)&si[1][px][sr] = wb;                                              \
    *(f16x4*)&si[2][px][sr] = ws;                                              \
    *(f16x4*)&si[3][px][sr] = wp;                                              \
  }

// H phase: pinned 2-deep rolling pipeline (counted vmcnt by construction).
template <bool MASKED>
__device__ __forceinline__ void h_phase(
    const float* __restrict__ p1, const float* __restrict__ p2,
    f16 (*si)[64][ROWS],
    int gy0, int xb, int px, int n, int kg, const f16x8& Bh)
{
  float4 A0[2], A1[2], B0[2], B1[2];   // static indices after expansion
  float ok[2];
  H_ISSUE(0, 0)
  H_ISSUE(1, 1)
  __builtin_amdgcn_sched_barrier(0);
  H_CONSUME(0, 0)
  H_ISSUE(2, 0)
  __builtin_amdgcn_sched_barrier(0);
  H_CONSUME(1, 1)
  H_ISSUE(3, 1)
  __builtin_amdgcn_sched_barrier(0);
  H_CONSUME(2, 0)
  H_ISSUE(4, 0)
  __builtin_amdgcn_sched_barrier(0);
  H_CONSUME(3, 1)
  H_CONSUME(4, 0)
}

__global__ __launch_bounds__(NTHREADS) void ssim_main_kernel(
    const float* __restrict__ img1, const float* __restrict__ img2,
    float* __restrict__ partials, float norm, float cexp)
{
  // transposed h-blur fields: si[field][px(64)][row(88)], f16. 45,056 B.
  // Columns [16*wv,16*wv+16) are PRIVATE to wave wv -> barrier-free pipeline
  // (same-wave DS ordering; verified R20 absmax 0).
  __shared__ f16 si[4][64][ROWS];
  __shared__ float sred[4];

  const int tid = threadIdx.x;
  const int wv = tid >> 6, lane = tid & 63;
  const int n = lane & 15, kg = lane >> 4;

  int b = blockIdx.x;
  const int tx = b & 7; b >>= 3;
  const int ty = b & 7; b >>= 3;
  const float* __restrict__ p1 = img1 + (size_t)b * 262144;
  const float* __restrict__ p2 = img2 + (size_t)b * 262144;

  // ---- constant tap fragments ----
  // h: B[k][n] = g[k-n-3]; v: A[o][kr] = g[kr-o]; k = 8*kg+i
  f16x8 Bh, Av;
#pragma unroll
  for (int i = 0; i < 8; i++) {
    const int k = 8 * kg + i;
    {
      const int idx = k - n - 3;
      const float d = (float)(idx - 5);
      const float val = norm * exp2f(cexp * d * d);
      Bh[i] = (idx >= 0 && idx <= 10) ? (f16)val : (f16)0.f;
    }
    {
      const int idx = k - n;
      const float d = (float)(idx - 5);
      const float val = norm * exp2f(cexp * d * d);
      Av[i] = (idx >= 0 && idx <= 10) ? (f16)val : (f16)0.f;
    }
  }

  // ---- geometry ----
  const int X0 = tx * 64 + wv * 16;      // this wave's out-x base
  const int xb = X0 - 8 + 8 * kg;        // this lane's sample-octet base
  const int gy0 = ty * 64 - 5;
  const int px = wv * 16 + n;            // this lane's si column

  // ================= H phase (barrier-free, pipelined) =================
  const bool interior = (tx >= 1) && (tx <= 6) && (ty >= 1) && (ty <= 6);
  if (interior)
    h_phase<false>(p1, p2, si, gy0, xb, px, n, kg, Bh);
  else
    h_phase<true>(p1, p2, si, gy0, xb, px, n, kg, Bh);

  // ================= V phase: 4 output-row groups of 16 =================
  float acc4[4] = {0.f, 0.f, 0.f, 0.f};
#pragma unroll
  for (int og = 0; og < 4; og++) {
    const int srb = og * 16 + 8 * kg;    // B k-slice rows (contiguous 8)
    const f16x8 Ba = *(const f16x8*)&si[0][px][srb];
    const f16x8 Bb = *(const f16x8*)&si[1][px][srb];
    const f16x8 Bs = *(const f16x8*)&si[2][px][srb];
    const f16x8 Bp = *(const f16x8*)&si[3][px][srb];
    const f32x4 z = {0.f, 0.f, 0.f, 0.f};
    const f32x4 Ma = __builtin_amdgcn_mfma_f32_16x16x32_f16(Av, Ba, z, 0, 0, 0);
    const f32x4 Mb = __builtin_amdgcn_mfma_f32_16x16x32_f16(Av, Bb, z, 0, 0, 0);
    const f32x4 Ms = __builtin_amdgcn_mfma_f32_16x16x32_f16(Av, Bs, z, 0, 0, 0);
    const f32x4 Mp = __builtin_amdgcn_mfma_f32_16x16x32_f16(Av, Bp, z, 0, 0, 0);
    // D: col = x (lane&15), row = out-row og*16 + kg*4 + reg; all rows valid
#pragma unroll
    for (int r = 0; r < 4; r++)
      acc4[r] += ssim_px(Ma[r], Mb[r], Ms[r], Mp[r]);
  }
  float accSum = (acc4[0] + acc4[1]) + (acc4[2] + acc4[3]);

  // ---- block reduction (only barrier in the kernel) ----
  for (int off = 32; off > 0; off >>= 1)
    accSum += __shfl_down(accSum, off, 64);
  if (lane == 0) sred[wv] = accSum;
  __syncthreads();
  if (tid == 0)
    partials[blockIdx.x] = sred[0] + sred[1] + sred[2] + sred[3];
}

__global__ __launch_bounds__(256) void ssim_final_kernel(
    const float* __restrict__ partials, float* __restrict__ out,
    int n, double invN)
{
  __shared__ double sred[4];
  const int tid = threadIdx.x;
  double s = 0.0;
  for (int i = tid; i < n; i += 256) s += (double)partials[i];
  for (int off = 32; off > 0; off >>= 1)
    s += __shfl_down(s, off, 64);
  if ((tid & 63) == 0) sred[tid >> 6] = s;
  __syncthreads();
  if (tid == 0) {
    double tot = 0.0;
#pragma unroll
    for (int i = 0; i < 4; i++) tot += sred[i];
    out[0] = (float)(1.0 - tot * invN);
  }
}

extern "C" void kernel_launch(void* const* d_in, const int* in_sizes, int n_in,
                              void* d_out, int out_size, void* d_ws, size_t ws_size,
                              hipStream_t stream) {
  const float* img1 = (const float*)d_in[0];
  const float* img2 = (const float*)d_in[1];
  float* out = (float*)d_out;
  float* partials = (float*)d_ws;

  const int planes = in_sizes[0] / (512 * 512);   // 96
  const int nBlocks = planes * 8 * 8;             // 6144

  // taps: g(idx) = norm * exp2(cexp * (idx-5)^2), idx in [0,10]
  double sum = 0.0;
  for (int i = 0; i < 11; i++) {
    const double x = (double)(i - 5);
    sum += exp(-(x * x) / 4.5);
  }
  const float norm = (float)(1.0 / sum);
  const float cexp = (float)(-1.0 / (4.5 * 0.6931471805599453));

  const double invN = 1.0 / (double)in_sizes[0];

  ssim_main_kernel<<<nBlocks, NTHREADS, 0, stream>>>(img1, img2, partials, norm, cexp);
  ssim_final_kernel<<<1, 256, 0, stream>>>(partials, out, nBlocks, invN);
}